// Round 2
// baseline (1158.409 us; speedup 1.0000x reference)
//
#include <hip/hip_runtime.h>

#define B_   2
#define SQ_  2048
#define DM_  1024
#define NH_  16
#define DH_  64

__device__ __forceinline__ float gsum16(float v) {
    v += __shfl_xor(v, 1);
    v += __shfl_xor(v, 2);
    v += __shfl_xor(v, 4);
    v += __shfl_xor(v, 8);
    return v;
}
__device__ __forceinline__ float gmax16(float v) {
    v = fmaxf(v, __shfl_xor(v, 1));
    v = fmaxf(v, __shfl_xor(v, 2));
    v = fmaxf(v, __shfl_xor(v, 4));
    v = fmaxf(v, __shfl_xor(v, 8));
    return v;
}

// C[M=4096, N=1024] = X[4096,1024] * W + bias, optional per-64-col (per-head) LN.
// Weight element B[k][c] lives at W[(c>>6)*wsA + k*wsB + (c&63)]:
//   QKV weights (n,d,h):  wsA=65536, wsB=64
//   W_O flat   (r,d):     wsA=64,    wsB=1024
template <bool DO_LN>
__global__ __launch_bounds__(256) void proj_gemm(
    const float* __restrict__ X, const float* __restrict__ W,
    const float* __restrict__ bias, const float* __restrict__ lnw,
    const float* __restrict__ lnb, float* __restrict__ C, int wsA, int wsB)
{
    __shared__ float As[16][68];   // X^T tile: As[k][m]
    __shared__ float Bs[16][68];   // W tile:   Bs[k][c]

    const int tid = threadIdx.x;
    const int tr = tid >> 4;       // 0..15 -> rows tr*4..+3
    const int tc = tid & 15;       // 0..15 -> cols tc*4..+3
    const int m0 = blockIdx.y * 64;
    const int c0 = blockIdx.x * 64;

    const int lm = tid >> 2;             // X-load row 0..63
    const int lk = (tid & 3) * 4;        // X-load k offset
    const int wk = tid >> 4;             // W-load k 0..15
    const int wc = (tid & 15) * 4;       // W-load col offset

    const float* xp = X + (size_t)(m0 + lm) * DM_ + lk;
    const float* wp = W + (size_t)(c0 >> 6) * wsA + (size_t)wk * wsB + wc;

    float acc[4][4] = {{0.f, 0.f, 0.f, 0.f}, {0.f, 0.f, 0.f, 0.f},
                       {0.f, 0.f, 0.f, 0.f}, {0.f, 0.f, 0.f, 0.f}};

    for (int k0 = 0; k0 < DM_; k0 += 16) {
        const float4 xv = *(const float4*)(xp + k0);
        const float4 wv = *(const float4*)(wp + (size_t)k0 * wsB);
        __syncthreads();
        As[lk + 0][lm] = xv.x;
        As[lk + 1][lm] = xv.y;
        As[lk + 2][lm] = xv.z;
        As[lk + 3][lm] = xv.w;
        *(float4*)&Bs[wk][wc] = wv;
        __syncthreads();
#pragma unroll
        for (int kk = 0; kk < 16; ++kk) {
            const float4 a4 = *(const float4*)&As[kk][tr * 4];
            const float4 b4 = *(const float4*)&Bs[kk][tc * 4];
            const float a[4] = {a4.x, a4.y, a4.z, a4.w};
            const float b[4] = {b4.x, b4.y, b4.z, b4.w};
#pragma unroll
            for (int i = 0; i < 4; ++i)
#pragma unroll
                for (int j = 0; j < 4; ++j)
                    acc[i][j] = fmaf(a[i], b[j], acc[i][j]);
        }
    }

    float bv[4];
#pragma unroll
    for (int j = 0; j < 4; ++j) bv[j] = bias[c0 + tc * 4 + j];
#pragma unroll
    for (int i = 0; i < 4; ++i)
#pragma unroll
        for (int j = 0; j < 4; ++j) acc[i][j] += bv[j];

    if constexpr (DO_LN) {
        // per-head LN over the 64 cols of this tile (tile == one head)
#pragma unroll
        for (int i = 0; i < 4; ++i) {
            float s = acc[i][0] + acc[i][1] + acc[i][2] + acc[i][3];
            const float mu = gsum16(s) * (1.0f / 64.0f);
            float s2 = acc[i][0] * acc[i][0] + acc[i][1] * acc[i][1] +
                       acc[i][2] * acc[i][2] + acc[i][3] * acc[i][3];
            const float var = gsum16(s2) * (1.0f / 64.0f) - mu * mu;
            const float rstd = rsqrtf(var + 1e-5f);
#pragma unroll
            for (int j = 0; j < 4; ++j) {
                const float w = lnw[tc * 4 + j];
                const float bb = lnb[tc * 4 + j];
                acc[i][j] = (acc[i][j] - mu) * rstd * w + bb;
            }
        }
    }

#pragma unroll
    for (int i = 0; i < 4; ++i) {
        float4 o = make_float4(acc[i][0], acc[i][1], acc[i][2], acc[i][3]);
        *(float4*)&C[(size_t)(m0 + tr * 4 + i) * DM_ + c0 + tc * 4] = o;
    }
}

// load one 64x64 f32 tile (row stride DM_) into padded LDS
__device__ __forceinline__ void load_tile64(const float* __restrict__ src_base,
                                            float dst[64][68], int tid)
{
    const int lr = tid >> 2;          // 0..63
    const int lc = (tid & 3) * 16;    // 0,16,32,48
    const float* src = src_base + (size_t)lr * DM_ + lc;
#pragma unroll
    for (int p = 0; p < 16; p += 4) {
        const float4 u = *(const float4*)&src[p];
        dst[lr][lc + p + 0] = u.x;
        dst[lr][lc + p + 1] = u.y;
        dst[lr][lc + p + 2] = u.z;
        dst[lr][lc + p + 3] = u.w;
    }
}

// causal flash attention, 64 q-rows per block, d_head=64, no 1/sqrt(d) scaling
__global__ __launch_bounds__(256) void attn_kernel(
    const float* __restrict__ qws, const float* __restrict__ kout,
    const float* __restrict__ vout, float* __restrict__ zws)
{
    __shared__ float Qs[64][68];
    __shared__ float KVs[64][68];   // holds K, then V, each kt iteration
    __shared__ float Ps[64][68];

    const int tid = threadIdx.x;
    const int tr = tid >> 4;    // rows tr*4..+3
    const int tc = tid & 15;    // S-cols / head-dims tc*4..+3
    const int qt = blockIdx.x;  // q tile 0..31
    const int h  = blockIdx.y;  // head
    const int b  = blockIdx.z;  // batch

    const size_t qbase  = ((size_t)b * SQ_ + (size_t)qt * 64) * DM_ + h * DH_;
    const size_t kvbase = (size_t)b * SQ_ * DM_ + h * DH_;

    load_tile64(qws + qbase, Qs, tid);

    float m_i[4], l_i[4], z[4][4];
#pragma unroll
    for (int i = 0; i < 4; ++i) {
        m_i[i] = -INFINITY;
        l_i[i] = 0.f;
#pragma unroll
        for (int j = 0; j < 4; ++j) z[i][j] = 0.f;
    }
    __syncthreads();

    for (int kt = 0; kt <= qt; ++kt) {
        load_tile64(kout + kvbase + (size_t)kt * 64 * DM_, KVs, tid);
        __syncthreads();

        // S = Q * K^T  (4x4 per thread)
        float s[4][4] = {{0.f, 0.f, 0.f, 0.f}, {0.f, 0.f, 0.f, 0.f},
                         {0.f, 0.f, 0.f, 0.f}, {0.f, 0.f, 0.f, 0.f}};
#pragma unroll 4
        for (int h4 = 0; h4 < 64; h4 += 4) {
            float qv[4][4], kv[4][4];
#pragma unroll
            for (int i = 0; i < 4; ++i) {
                const float4 t = *(const float4*)&Qs[tr * 4 + i][h4];
                qv[i][0] = t.x; qv[i][1] = t.y; qv[i][2] = t.z; qv[i][3] = t.w;
            }
#pragma unroll
            for (int j = 0; j < 4; ++j) {
                const float4 t = *(const float4*)&KVs[tc * 4 + j][h4];
                kv[j][0] = t.x; kv[j][1] = t.y; kv[j][2] = t.z; kv[j][3] = t.w;
            }
#pragma unroll
            for (int i = 0; i < 4; ++i)
#pragma unroll
                for (int j = 0; j < 4; ++j)
#pragma unroll
                    for (int d = 0; d < 4; ++d)
                        s[i][j] = fmaf(qv[i][d], kv[j][d], s[i][j]);
        }

        if (kt == qt) {   // diagonal tile: causal mask
#pragma unroll
            for (int i = 0; i < 4; ++i)
#pragma unroll
                for (int j = 0; j < 4; ++j)
                    if (tc * 4 + j > tr * 4 + i) s[i][j] = -3.0e38f;
        }

        // online softmax update (row groups of 16 lanes)
        float alpha[4];
#pragma unroll
        for (int i = 0; i < 4; ++i) {
            float rmax = fmaxf(fmaxf(s[i][0], s[i][1]), fmaxf(s[i][2], s[i][3]));
            rmax = gmax16(rmax);
            const float mn = fmaxf(m_i[i], rmax);
            alpha[i] = (m_i[i] == -INFINITY) ? 0.f : __expf(m_i[i] - mn);
            float rs = 0.f;
#pragma unroll
            for (int j = 0; j < 4; ++j) {
                s[i][j] = __expf(s[i][j] - mn);
                rs += s[i][j];
            }
            rs = gsum16(rs);
            l_i[i] = l_i[i] * alpha[i] + rs;
            m_i[i] = mn;
#pragma unroll
            for (int j = 0; j < 4; ++j) {
                Ps[tr * 4 + i][tc * 4 + j] = s[i][j];
                z[i][j] *= alpha[i];
            }
        }
        __syncthreads();   // P written; all K reads done

        load_tile64(vout + kvbase + (size_t)kt * 64 * DM_, KVs, tid);
        __syncthreads();

        // z += P * V
#pragma unroll 4
        for (int c4 = 0; c4 < 64; c4 += 4) {
            float pv[4][4], vv[4][4];
#pragma unroll
            for (int i = 0; i < 4; ++i) {
                const float4 t = *(const float4*)&Ps[tr * 4 + i][c4];
                pv[i][0] = t.x; pv[i][1] = t.y; pv[i][2] = t.z; pv[i][3] = t.w;
            }
#pragma unroll
            for (int cc = 0; cc < 4; ++cc) {
                const float4 t = *(const float4*)&KVs[c4 + cc][tc * 4];
                vv[cc][0] = t.x; vv[cc][1] = t.y; vv[cc][2] = t.z; vv[cc][3] = t.w;
            }
#pragma unroll
            for (int i = 0; i < 4; ++i)
#pragma unroll
                for (int cc = 0; cc < 4; ++cc)
#pragma unroll
                    for (int j = 0; j < 4; ++j)
                        z[i][j] = fmaf(pv[i][cc], vv[cc][j], z[i][j]);
        }
        __syncthreads();   // done with KVs/Ps before next iteration
    }

#pragma unroll
    for (int i = 0; i < 4; ++i) {
        const float inv = 1.0f / l_i[i];
        float4 o = make_float4(z[i][0] * inv, z[i][1] * inv,
                               z[i][2] * inv, z[i][3] * inv);
        *(float4*)&zws[qbase + (size_t)(tr * 4 + i) * DM_ + tc * 4] = o;
    }
}

extern "C" void kernel_launch(void* const* d_in, const int* in_sizes, int n_in,
                              void* d_out, int out_size, void* d_ws, size_t ws_size,
                              hipStream_t stream)
{
    const float* x_q  = (const float*)d_in[0];
    const float* x_kv = (const float*)d_in[1];
    // d_in[2] = mask (causal tril) -- computed analytically, not read
    const float* W_Q  = (const float*)d_in[3];
    const float* W_K  = (const float*)d_in[4];
    const float* W_V  = (const float*)d_in[5];
    const float* W_O  = (const float*)d_in[6];
    const float* b_Q  = (const float*)d_in[7];
    const float* b_K  = (const float*)d_in[8];
    const float* b_V  = (const float*)d_in[9];
    const float* b_O  = (const float*)d_in[10];
    const float* ln1w = (const float*)d_in[11];
    const float* ln1b = (const float*)d_in[12];
    const float* ln2w = (const float*)d_in[13];
    const float* ln2b = (const float*)d_in[14];

    const size_t NTOK = (size_t)B_ * SQ_;          // 4096
    float* out  = (float*)d_out;                   // (B,SQ,DM)
    float* kout = out + NTOK * DM_;                // (B,SK,NH,DH), post-LN
    float* vout = kout + NTOK * DM_;               // (B,SK,NH,DH)
    float* qws  = (float*)d_ws;                    // LN'd q, (B,SQ,NH,DH)
    float* zws  = qws + NTOK * DM_;                // attention output z

    dim3 blk(256);
    dim3 gg(DM_ / 64, NTOK / 64);                  // (16, 64)

    proj_gemm<true><<<gg, blk, 0, stream>>>(x_q,  W_Q, b_Q, ln1w, ln1b, qws,  65536, 64);
    proj_gemm<true><<<gg, blk, 0, stream>>>(x_kv, W_K, b_K, ln2w, ln2b, kout, 65536, 64);
    proj_gemm<false><<<gg, blk, 0, stream>>>(x_kv, W_V, b_V, nullptr, nullptr, vout, 65536, 64);

    attn_kernel<<<dim3(SQ_ / 64, NH_, B_), blk, 0, stream>>>(qws, kout, vout, zws);

    proj_gemm<false><<<gg, blk, 0, stream>>>(zws, W_O, b_O, nullptr, nullptr, out, 64, 1024);
}

// Round 3
// 412.742 us; speedup vs baseline: 2.8066x; 2.8066x over previous
//
#include <hip/hip_runtime.h>
#include <hip/hip_bf16.h>

#define B_   2
#define SQ_  2048
#define DM_  1024
#define NH_  16
#define DH_  64

typedef __attribute__((ext_vector_type(8))) short          bf16x8;
typedef __attribute__((ext_vector_type(8))) unsigned short u16x8;
typedef __attribute__((ext_vector_type(4))) float          f32x4;

__device__ __forceinline__ unsigned short f2bf(float f) {
    union { __hip_bfloat16 h; unsigned short u; } c;
    c.h = __float2bfloat16(f);   // RNE
    return c.u;
}
__device__ __forceinline__ float gsum16(float v) {
    v += __shfl_xor(v, 1);
    v += __shfl_xor(v, 2);
    v += __shfl_xor(v, 4);
    v += __shfl_xor(v, 8);
    return v;
}
__device__ __forceinline__ float gmax16(float v) {
    v = fmaxf(v, __shfl_xor(v, 1));
    v = fmaxf(v, __shfl_xor(v, 2));
    v = fmaxf(v, __shfl_xor(v, 4));
    v = fmaxf(v, __shfl_xor(v, 8));
    return v;
}

// dst[c][r] = bf16(src[r][c]) per matrix (blockIdx.z); R,C multiples of 64.
__global__ __launch_bounds__(256) void transpose_w(
    const float* __restrict__ src, unsigned short* __restrict__ dst, int R, int C)
{
    __shared__ float t[64][65];
    const int r0 = blockIdx.x * 64, c0 = blockIdx.y * 64;
    const size_t ms = (size_t)R * C * blockIdx.z;
    src += ms; dst += ms;
    const int lr = threadIdx.x >> 6, lc = threadIdx.x & 63;
#pragma unroll
    for (int i = 0; i < 16; ++i) {
        const int row = lr + i * 4;
        t[row][lc] = src[(size_t)(r0 + row) * C + c0 + lc];
    }
    __syncthreads();
#pragma unroll
    for (int i = 0; i < 16; ++i) {
        const int crow = lr + i * 4;
        dst[(size_t)(c0 + crow) * R + r0 + lc] = f2bf(t[lc][crow]);
    }
}

// C[4096 x 1024] = A[4096 x 1024] * W  (+bias, optional per-head LN over 64 cols)
// W supplied transposed as bf16 WT[c][k], row stride 1024.
// A source: f32 (A_BF16=0) or bf16 (A_BF16=1), row stride 1024.
// Tile 128x128, 4 waves each 64x64, BK=64, mfma_f32_16x16x32_bf16.
template <int A_BF16, int DO_LN, int W_F32, int W_BF16>
__global__ __launch_bounds__(256) void mfma_gemm(
    const void* __restrict__ Asrc, const unsigned short* __restrict__ WT,
    const float* __restrict__ bias, const float* __restrict__ lnw,
    const float* __restrict__ lnb, float* __restrict__ Cf,
    unsigned short* __restrict__ Cb)
{
    __shared__ __align__(16) unsigned short As[128][72];  // [m][k], pad 8
    __shared__ __align__(16) unsigned short Bs[128][72];  // [c][k], pad 8

    const int tid = threadIdx.x;
    const int m0 = blockIdx.y * 128;
    const int c0 = blockIdx.x * 128;

    const int srow = tid >> 2;          // 0..63 (+64 on 2nd pass)
    const int skc  = (tid & 3) * 16;    // k offset within BK=64

    float4 fa[2][4];
    u16x8  ba[2][2];
    u16x8  bb[2][2];

    auto loadA = [&](int kb) {
        const size_t kof = (size_t)kb * 64 + skc;
        if constexpr (!A_BF16) {
            const float* A = (const float*)Asrc;
#pragma unroll
            for (int p = 0; p < 2; ++p) {
                const float* s = A + (size_t)(m0 + srow + p * 64) * 1024 + kof;
                fa[p][0] = *(const float4*)(s + 0);
                fa[p][1] = *(const float4*)(s + 4);
                fa[p][2] = *(const float4*)(s + 8);
                fa[p][3] = *(const float4*)(s + 12);
            }
        } else {
            const unsigned short* A = (const unsigned short*)Asrc;
#pragma unroll
            for (int p = 0; p < 2; ++p) {
                const unsigned short* s = A + (size_t)(m0 + srow + p * 64) * 1024 + kof;
                ba[p][0] = *(const u16x8*)(s + 0);
                ba[p][1] = *(const u16x8*)(s + 8);
            }
        }
    };
    auto loadB = [&](int kb) {
        const size_t kof = (size_t)kb * 64 + skc;
#pragma unroll
        for (int p = 0; p < 2; ++p) {
            const unsigned short* s = WT + (size_t)(c0 + srow + p * 64) * 1024 + kof;
            bb[p][0] = *(const u16x8*)(s + 0);
            bb[p][1] = *(const u16x8*)(s + 8);
        }
    };
    auto writeLDS = [&]() {
#pragma unroll
        for (int p = 0; p < 2; ++p) {
            if constexpr (!A_BF16) {
                u16x8 lo, hi;
                lo[0] = f2bf(fa[p][0].x); lo[1] = f2bf(fa[p][0].y);
                lo[2] = f2bf(fa[p][0].z); lo[3] = f2bf(fa[p][0].w);
                lo[4] = f2bf(fa[p][1].x); lo[5] = f2bf(fa[p][1].y);
                lo[6] = f2bf(fa[p][1].z); lo[7] = f2bf(fa[p][1].w);
                hi[0] = f2bf(fa[p][2].x); hi[1] = f2bf(fa[p][2].y);
                hi[2] = f2bf(fa[p][2].z); hi[3] = f2bf(fa[p][2].w);
                hi[4] = f2bf(fa[p][3].x); hi[5] = f2bf(fa[p][3].y);
                hi[6] = f2bf(fa[p][3].z); hi[7] = f2bf(fa[p][3].w);
                *(u16x8*)&As[srow + p * 64][skc + 0] = lo;
                *(u16x8*)&As[srow + p * 64][skc + 8] = hi;
            } else {
                *(u16x8*)&As[srow + p * 64][skc + 0] = ba[p][0];
                *(u16x8*)&As[srow + p * 64][skc + 8] = ba[p][1];
            }
            *(u16x8*)&Bs[srow + p * 64][skc + 0] = bb[p][0];
            *(u16x8*)&Bs[srow + p * 64][skc + 8] = bb[p][1];
        }
    };

    const int wid = tid >> 6, lane = tid & 63;
    const int wm = (wid >> 1) * 64, wn = (wid & 1) * 64;
    const int l15 = lane & 15, qd = lane >> 4;

    const f32x4 zero4 = {0.f, 0.f, 0.f, 0.f};
    f32x4 acc[4][4];
#pragma unroll
    for (int mi = 0; mi < 4; ++mi)
#pragma unroll
        for (int ni = 0; ni < 4; ++ni) acc[mi][ni] = zero4;

    loadA(0); loadB(0);
    for (int kb = 0; kb < 16; ++kb) {
        __syncthreads();
        writeLDS();
        __syncthreads();
        if (kb < 15) { loadA(kb + 1); loadB(kb + 1); }
#pragma unroll
        for (int ks = 0; ks < 2; ++ks) {
            bf16x8 af[4], bfb[4];
#pragma unroll
            for (int mi = 0; mi < 4; ++mi)
                af[mi] = *(const bf16x8*)&As[wm + mi * 16 + l15][ks * 32 + qd * 8];
#pragma unroll
            for (int ni = 0; ni < 4; ++ni)
                bfb[ni] = *(const bf16x8*)&Bs[wn + ni * 16 + l15][ks * 32 + qd * 8];
#pragma unroll
            for (int mi = 0; mi < 4; ++mi)
#pragma unroll
                for (int ni = 0; ni < 4; ++ni)
                    acc[mi][ni] = __builtin_amdgcn_mfma_f32_16x16x32_bf16(
                        af[mi], bfb[ni], acc[mi][ni], 0, 0, 0);
        }
    }

    // epilogue: bias (+ LN) + stores.  C/D layout: row = qd*4+r, col = l15.
    float bv[4];
#pragma unroll
    for (int ni = 0; ni < 4; ++ni) bv[ni] = bias[c0 + wn + ni * 16 + l15];
#pragma unroll
    for (int mi = 0; mi < 4; ++mi)
#pragma unroll
        for (int ni = 0; ni < 4; ++ni)
#pragma unroll
            for (int r = 0; r < 4; ++r) acc[mi][ni][r] += bv[ni];

    if constexpr (DO_LN) {
        float w4[4], lb4[4];
#pragma unroll
        for (int ni = 0; ni < 4; ++ni) {
            w4[ni]  = lnw[ni * 16 + l15];
            lb4[ni] = lnb[ni * 16 + l15];
        }
#pragma unroll
        for (int mi = 0; mi < 4; ++mi)
#pragma unroll
            for (int r = 0; r < 4; ++r) {
                float s1 = acc[mi][0][r] + acc[mi][1][r] + acc[mi][2][r] + acc[mi][3][r];
                const float mu = gsum16(s1) * (1.0f / 64.0f);
                float s2 = acc[mi][0][r] * acc[mi][0][r] + acc[mi][1][r] * acc[mi][1][r]
                         + acc[mi][2][r] * acc[mi][2][r] + acc[mi][3][r] * acc[mi][3][r];
                const float var = gsum16(s2) * (1.0f / 64.0f) - mu * mu;
                const float rstd = rsqrtf(var + 1e-5f);
#pragma unroll
                for (int ni = 0; ni < 4; ++ni)
                    acc[mi][ni][r] = (acc[mi][ni][r] - mu) * rstd * w4[ni] + lb4[ni];
            }
    }

#pragma unroll
    for (int mi = 0; mi < 4; ++mi)
#pragma unroll
        for (int r = 0; r < 4; ++r) {
            const size_t grow = m0 + wm + mi * 16 + qd * 4 + r;
#pragma unroll
            for (int ni = 0; ni < 4; ++ni) {
                const int gcol = c0 + wn + ni * 16 + l15;
                if constexpr (W_F32)  Cf[grow * 1024 + gcol] = acc[mi][ni][r];
                if constexpr (W_BF16) Cb[grow * 1024 + gcol] = f2bf(acc[mi][ni][r]);
            }
        }
}

// causal flash attention with MFMA; 64 q-rows/block (4 waves x 16 rows),
// d_head=64, no 1/sqrt(d) scaling. z written bf16 in-place over qz.
__global__ __launch_bounds__(256) void attn_mfma(
    unsigned short* __restrict__ qz, const unsigned short* __restrict__ kbf,
    const unsigned short* __restrict__ vbf)
{
    __shared__ __align__(16) unsigned short Qs[64][72];    // [qrow][dh]
    __shared__ __align__(16) unsigned short Ks[64][72];    // [kvrow][dh]
    __shared__ __align__(16) unsigned short VsT[64][72];   // [dh][kvrow]
    __shared__ __align__(16) unsigned short Ps[64][72];    // [qrow][kvcol]

    const int tid = threadIdx.x;
    const int qt = blockIdx.x, h = blockIdx.y, b = blockIdx.z;
    const int wid = tid >> 6, lane = tid & 63;
    const int l15 = lane & 15, qd = lane >> 4;

    const size_t base = (size_t)b * SQ_ * DM_ + (size_t)h * DH_;

    {   // stage Q tile
        const int row = tid >> 2, c = (tid & 3) * 16;
        const unsigned short* s = qz + base + (size_t)(qt * 64 + row) * DM_ + c;
        *(u16x8*)&Qs[row][c + 0] = *(const u16x8*)(s + 0);
        *(u16x8*)&Qs[row][c + 8] = *(const u16x8*)(s + 8);
    }

    const f32x4 zero4 = {0.f, 0.f, 0.f, 0.f};
    f32x4 z[4];
    float m_i[4], l_i[4];
#pragma unroll
    for (int ni = 0; ni < 4; ++ni) z[ni] = zero4;
#pragma unroll
    for (int r = 0; r < 4; ++r) { m_i[r] = -3.0e38f; l_i[r] = 0.f; }

    for (int kt = 0; kt <= qt; ++kt) {
        __syncthreads();   // prior PV reads of VsT/Ps done
        {   // stage K (natural) and V (transposed)
            const int row = tid >> 2, c = (tid & 3) * 16;
            const unsigned short* ks = kbf + base + (size_t)(kt * 64 + row) * DM_ + c;
            *(u16x8*)&Ks[row][c + 0] = *(const u16x8*)(ks + 0);
            *(u16x8*)&Ks[row][c + 8] = *(const u16x8*)(ks + 8);
            const unsigned short* vs = vbf + base + (size_t)(kt * 64 + row) * DM_ + c;
            const u16x8 v0 = *(const u16x8*)(vs + 0);
            const u16x8 v1 = *(const u16x8*)(vs + 8);
#pragma unroll
            for (int j = 0; j < 8; ++j) VsT[c + j][row] = v0[j];
#pragma unroll
            for (int j = 0; j < 8; ++j) VsT[c + 8 + j][row] = v1[j];
        }
        __syncthreads();

        // S = Q K^T : wave rows wid*16..+15, cols 0..63 of this kv tile
        f32x4 s[4];
#pragma unroll
        for (int ni = 0; ni < 4; ++ni) s[ni] = zero4;
#pragma unroll
        for (int ks = 0; ks < 2; ++ks) {
            const bf16x8 aq = *(const bf16x8*)&Qs[wid * 16 + l15][ks * 32 + qd * 8];
#pragma unroll
            for (int ni = 0; ni < 4; ++ni) {
                const bf16x8 bk = *(const bf16x8*)&Ks[ni * 16 + l15][ks * 32 + qd * 8];
                s[ni] = __builtin_amdgcn_mfma_f32_16x16x32_bf16(aq, bk, s[ni], 0, 0, 0);
            }
        }

        if (kt == qt) {   // diagonal: mask kvcol > qrow (tile-local indices)
#pragma unroll
            for (int ni = 0; ni < 4; ++ni)
#pragma unroll
                for (int r = 0; r < 4; ++r)
                    if (ni * 16 + l15 > wid * 16 + qd * 4 + r) s[ni][r] = -3.0e38f;
        }

        float alpha[4];
#pragma unroll
        for (int r = 0; r < 4; ++r) {
            float rm = fmaxf(fmaxf(s[0][r], s[1][r]), fmaxf(s[2][r], s[3][r]));
            rm = gmax16(rm);
            const float mn = fmaxf(m_i[r], rm);
            alpha[r] = __expf(m_i[r] - mn);
            float rs = 0.f;
#pragma unroll
            for (int ni = 0; ni < 4; ++ni) {
                const float e = __expf(s[ni][r] - mn);
                s[ni][r] = e;
                rs += e;
            }
            rs = gsum16(rs);
            l_i[r] = l_i[r] * alpha[r] + rs;
            m_i[r] = mn;
        }
        // P (C-layout) -> LDS in A-operand-friendly [row][col]
#pragma unroll
        for (int r = 0; r < 4; ++r)
#pragma unroll
            for (int ni = 0; ni < 4; ++ni)
                Ps[wid * 16 + qd * 4 + r][ni * 16 + l15] = f2bf(s[ni][r]);
#pragma unroll
        for (int ni = 0; ni < 4; ++ni)
#pragma unroll
            for (int r = 0; r < 4; ++r) z[ni][r] *= alpha[r];
        __syncthreads();

        // z += P V
#pragma unroll
        for (int ks = 0; ks < 2; ++ks) {
            const bf16x8 ap = *(const bf16x8*)&Ps[wid * 16 + l15][ks * 32 + qd * 8];
#pragma unroll
            for (int ni = 0; ni < 4; ++ni) {
                const bf16x8 bv = *(const bf16x8*)&VsT[ni * 16 + l15][ks * 32 + qd * 8];
                z[ni] = __builtin_amdgcn_mfma_f32_16x16x32_bf16(ap, bv, z[ni], 0, 0, 0);
            }
        }
    }

    // z / l -> bf16, in-place over this block's q tile
#pragma unroll
    for (int r = 0; r < 4; ++r) {
        const float inv = 1.0f / l_i[r];
        const size_t row = (size_t)qt * 64 + wid * 16 + qd * 4 + r;
#pragma unroll
        for (int ni = 0; ni < 4; ++ni)
            qz[base + row * DM_ + ni * 16 + l15] = f2bf(z[ni][r] * inv);
    }
}

extern "C" void kernel_launch(void* const* d_in, const int* in_sizes, int n_in,
                              void* d_out, int out_size, void* d_ws, size_t ws_size,
                              hipStream_t stream)
{
    const float* x_q  = (const float*)d_in[0];
    const float* x_kv = (const float*)d_in[1];
    // d_in[2] = mask (causal tril) -- computed analytically
    const float* W_Q  = (const float*)d_in[3];
    const float* W_K  = (const float*)d_in[4];
    const float* W_V  = (const float*)d_in[5];
    const float* W_O  = (const float*)d_in[6];
    const float* b_Q  = (const float*)d_in[7];
    const float* b_K  = (const float*)d_in[8];
    const float* b_V  = (const float*)d_in[9];
    const float* b_O  = (const float*)d_in[10];
    const float* ln1w = (const float*)d_in[11];
    const float* ln1b = (const float*)d_in[12];
    const float* ln2w = (const float*)d_in[13];
    const float* ln2b = (const float*)d_in[14];

    const size_t NTOK = (size_t)B_ * SQ_;          // 4096
    float* out  = (float*)d_out;
    float* kout = out + NTOK * DM_;
    float* vout = kout + NTOK * DM_;

    unsigned short* wsu = (unsigned short*)d_ws;
    unsigned short* WTq = wsu;                         // 1M elems each
    unsigned short* WTk = WTq + (1u << 20);
    unsigned short* WTv = WTk + (1u << 20);
    unsigned short* WTo = WTv + (1u << 20);
    unsigned short* qz  = WTo + (1u << 20);            // 4M elems each
    unsigned short* kbf = qz  + (1u << 22);
    unsigned short* vbf = kbf + (1u << 22);            // total 32 MiB

    transpose_w<<<dim3(16, 1, 16), 256, 0, stream>>>(W_Q, WTq, 1024, 64);
    transpose_w<<<dim3(16, 1, 16), 256, 0, stream>>>(W_K, WTk, 1024, 64);
    transpose_w<<<dim3(16, 1, 16), 256, 0, stream>>>(W_V, WTv, 1024, 64);
    transpose_w<<<dim3(16, 16, 1), 256, 0, stream>>>(W_O, WTo, 1024, 1024);

    dim3 gg(DM_ / 128, NTOK / 128);   // (8, 32)
    mfma_gemm<0, 1, 0, 1><<<gg, 256, 0, stream>>>(x_q,  WTq, b_Q, ln1w, ln1b, nullptr, qz);
    mfma_gemm<0, 1, 1, 1><<<gg, 256, 0, stream>>>(x_kv, WTk, b_K, ln2w, ln2b, kout, kbf);
    mfma_gemm<0, 0, 1, 1><<<gg, 256, 0, stream>>>(x_kv, WTv, b_V, nullptr, nullptr, vout, vbf);

    attn_mfma<<<dim3(SQ_ / 64, NH_, B_), 256, 0, stream>>>(qz, kbf, vbf);

    mfma_gemm<1, 0, 1, 0><<<gg, 256, 0, stream>>>(qz, WTo, b_O, nullptr, nullptr, out, nullptr);
}

// Round 4
// 278.327 us; speedup vs baseline: 4.1620x; 1.4829x over previous
//
#include <hip/hip_runtime.h>
#include <hip/hip_bf16.h>

#define B_   2
#define SQ_  2048
#define DM_  1024
#define NH_  16
#define DH_  64

typedef __attribute__((ext_vector_type(8))) short          bf16x8;
typedef __attribute__((ext_vector_type(8))) unsigned short u16x8;
typedef __attribute__((ext_vector_type(4))) float          f32x4;

__device__ __forceinline__ unsigned short f2bf(float f) {
    union { __hip_bfloat16 h; unsigned short u; } c;
    c.h = __float2bfloat16(f);   // RNE
    return c.u;
}
__device__ __forceinline__ float gsum16(float v) {
    v += __shfl_xor(v, 1);
    v += __shfl_xor(v, 2);
    v += __shfl_xor(v, 4);
    v += __shfl_xor(v, 8);
    return v;
}

// dst[c][r] = bf16(src[r][c]) per matrix (blockIdx.z); R,C multiples of 64.
__global__ __launch_bounds__(256) void transpose_w(
    const float* __restrict__ src, unsigned short* __restrict__ dst, int R, int C)
{
    __shared__ float t[64][65];
    const int r0 = blockIdx.x * 64, c0 = blockIdx.y * 64;
    const size_t ms = (size_t)R * C * blockIdx.z;
    src += ms; dst += ms;
    const int lr = threadIdx.x >> 6, lc = threadIdx.x & 63;
#pragma unroll
    for (int i = 0; i < 16; ++i) {
        const int row = lr + i * 4;
        t[row][lc] = src[(size_t)(r0 + row) * C + c0 + lc];
    }
    __syncthreads();
#pragma unroll
    for (int i = 0; i < 16; ++i) {
        const int crow = lr + i * 4;
        dst[(size_t)(c0 + crow) * R + r0 + lc] = f2bf(t[lc][crow]);
    }
}

// C[4096 x N] = A[4096 x 1024] * W(+bias).  WT bf16 [c][k], row stride 1024.
// TM=128, BK=64, 256 threads.
// TN=128: waves 2x2 (64x64 each).  TN=64: waves 4x1 (32x64 each).
// MODE 0: Q  -> per-head LN, bf16 out (Cb)
// MODE 1: KV -> N=2048; cols<1024: K (LN, f32 Cf + bf16 Cb); cols>=1024: V
//               (f32 Cf2 row-major + bf16 CbT transposed [b][h][d][s])
// MODE 2: O  -> f32 out (Cf)
template <int TN, int A_BF16, int MODE>
__global__ __launch_bounds__(256) void mfma_gemm(
    const void* __restrict__ Asrc, const unsigned short* __restrict__ WT,
    const float* __restrict__ biasK, const float* __restrict__ biasV,
    const float* __restrict__ lnw, const float* __restrict__ lnb,
    float* __restrict__ Cf, float* __restrict__ Cf2,
    unsigned short* __restrict__ Cb, unsigned short* __restrict__ CbT)
{
    constexpr int MI = (TN == 128) ? 4 : 2;   // 16-row tiles per wave
    constexpr int BP = TN / 64;               // B staging passes

    __shared__ __align__(16) unsigned short As[128][72];
    __shared__ __align__(16) unsigned short Bs[TN][72];

    const int tid = threadIdx.x;
    const int m0 = blockIdx.y * 128;
    const int c0 = blockIdx.x * TN;

    const int srow = tid >> 2;
    const int skc  = (tid & 3) * 16;

    float4 fa[2][4];
    u16x8  ba[2][2];
    u16x8  bb[BP][2];

    const int wid = tid >> 6, lane = tid & 63;
    const int wm = (TN == 128) ? (wid >> 1) * 64 : wid * 32;
    const int wn = (TN == 128) ? (wid & 1) * 64 : 0;
    const int l15 = lane & 15, qd = lane >> 4;

    const f32x4 zero4 = {0.f, 0.f, 0.f, 0.f};
    f32x4 acc[MI][4];
#pragma unroll
    for (int mi = 0; mi < MI; ++mi)
#pragma unroll
        for (int ni = 0; ni < 4; ++ni) acc[mi][ni] = zero4;

#define LOAD_A(kb)                                                              \
    {                                                                           \
        const size_t kof = (size_t)(kb) * 64 + skc;                             \
        if constexpr (!A_BF16) {                                                \
            const float* A = (const float*)Asrc;                                \
            for (int p = 0; p < 2; ++p) {                                       \
                const float* s = A + (size_t)(m0 + srow + p * 64) * 1024 + kof; \
                fa[p][0] = *(const float4*)(s + 0);                             \
                fa[p][1] = *(const float4*)(s + 4);                             \
                fa[p][2] = *(const float4*)(s + 8);                             \
                fa[p][3] = *(const float4*)(s + 12);                            \
            }                                                                   \
        } else {                                                                \
            const unsigned short* A = (const unsigned short*)Asrc;              \
            for (int p = 0; p < 2; ++p) {                                       \
                const unsigned short* s =                                       \
                    A + (size_t)(m0 + srow + p * 64) * 1024 + kof;              \
                ba[p][0] = *(const u16x8*)(s + 0);                              \
                ba[p][1] = *(const u16x8*)(s + 8);                              \
            }                                                                   \
        }                                                                       \
        for (int p = 0; p < BP; ++p) {                                          \
            const unsigned short* s =                                           \
                WT + (size_t)(c0 + srow + p * 64) * 1024 + kof;                 \
            bb[p][0] = *(const u16x8*)(s + 0);                                  \
            bb[p][1] = *(const u16x8*)(s + 8);                                  \
        }                                                                       \
    }

    LOAD_A(0)
    for (int kb = 0; kb < 16; ++kb) {
        __syncthreads();
#pragma unroll
        for (int p = 0; p < 2; ++p) {
            if constexpr (!A_BF16) {
                u16x8 lo, hi;
                lo[0] = f2bf(fa[p][0].x); lo[1] = f2bf(fa[p][0].y);
                lo[2] = f2bf(fa[p][0].z); lo[3] = f2bf(fa[p][0].w);
                lo[4] = f2bf(fa[p][1].x); lo[5] = f2bf(fa[p][1].y);
                lo[6] = f2bf(fa[p][1].z); lo[7] = f2bf(fa[p][1].w);
                hi[0] = f2bf(fa[p][2].x); hi[1] = f2bf(fa[p][2].y);
                hi[2] = f2bf(fa[p][2].z); hi[3] = f2bf(fa[p][2].w);
                hi[4] = f2bf(fa[p][3].x); hi[5] = f2bf(fa[p][3].y);
                hi[6] = f2bf(fa[p][3].z); hi[7] = f2bf(fa[p][3].w);
                *(u16x8*)&As[srow + p * 64][skc + 0] = lo;
                *(u16x8*)&As[srow + p * 64][skc + 8] = hi;
            } else {
                *(u16x8*)&As[srow + p * 64][skc + 0] = ba[p][0];
                *(u16x8*)&As[srow + p * 64][skc + 8] = ba[p][1];
            }
        }
#pragma unroll
        for (int p = 0; p < BP; ++p) {
            *(u16x8*)&Bs[srow + p * 64][skc + 0] = bb[p][0];
            *(u16x8*)&Bs[srow + p * 64][skc + 8] = bb[p][1];
        }
        __syncthreads();
        if (kb < 15) LOAD_A(kb + 1)
#pragma unroll
        for (int ks = 0; ks < 2; ++ks) {
            bf16x8 af[MI], bfr[4];
#pragma unroll
            for (int mi = 0; mi < MI; ++mi)
                af[mi] = *(const bf16x8*)&As[wm + mi * 16 + l15][ks * 32 + qd * 8];
#pragma unroll
            for (int ni = 0; ni < 4; ++ni)
                bfr[ni] = *(const bf16x8*)&Bs[wn + ni * 16 + l15][ks * 32 + qd * 8];
#pragma unroll
            for (int mi = 0; mi < MI; ++mi)
#pragma unroll
                for (int ni = 0; ni < 4; ++ni)
                    acc[mi][ni] = __builtin_amdgcn_mfma_f32_16x16x32_bf16(
                        af[mi], bfr[ni], acc[mi][ni], 0, 0, 0);
        }
    }
#undef LOAD_A

    const float* bias = (MODE == 1 && c0 >= 1024) ? biasV : biasK;
    float bv[4];
#pragma unroll
    for (int ni = 0; ni < 4; ++ni) bv[ni] = bias[(c0 + wn + ni * 16 + l15) & 1023];
#pragma unroll
    for (int mi = 0; mi < MI; ++mi)
#pragma unroll
        for (int ni = 0; ni < 4; ++ni)
#pragma unroll
            for (int r = 0; r < 4; ++r) acc[mi][ni][r] += bv[ni];

    if constexpr (MODE != 2) {
        const bool doLN = (MODE == 0) || (c0 < 1024);
        if (doLN) {   // per-head LN: wave's 64 cols = exactly one head
            float w4[4], lb4[4];
#pragma unroll
            for (int ni = 0; ni < 4; ++ni) {
                w4[ni]  = lnw[ni * 16 + l15];
                lb4[ni] = lnb[ni * 16 + l15];
            }
#pragma unroll
            for (int mi = 0; mi < MI; ++mi)
#pragma unroll
                for (int r = 0; r < 4; ++r) {
                    float s1 = acc[mi][0][r] + acc[mi][1][r] + acc[mi][2][r] + acc[mi][3][r];
                    const float mu = gsum16(s1) * (1.0f / 64.0f);
                    float s2 = acc[mi][0][r] * acc[mi][0][r] + acc[mi][1][r] * acc[mi][1][r]
                             + acc[mi][2][r] * acc[mi][2][r] + acc[mi][3][r] * acc[mi][3][r];
                    const float var = gsum16(s2) * (1.0f / 64.0f) - mu * mu;
                    const float rstd = rsqrtf(var + 1e-5f);
#pragma unroll
                    for (int ni = 0; ni < 4; ++ni)
                        acc[mi][ni][r] = (acc[mi][ni][r] - mu) * rstd * w4[ni] + lb4[ni];
                }
        }
    }

    if constexpr (MODE == 0) {
#pragma unroll
        for (int mi = 0; mi < MI; ++mi)
#pragma unroll
            for (int r = 0; r < 4; ++r) {
                const size_t grow = m0 + wm + mi * 16 + qd * 4 + r;
#pragma unroll
                for (int ni = 0; ni < 4; ++ni)
                    Cb[grow * 1024 + c0 + wn + ni * 16 + l15] = f2bf(acc[mi][ni][r]);
            }
    } else if constexpr (MODE == 2) {
#pragma unroll
        for (int mi = 0; mi < MI; ++mi)
#pragma unroll
            for (int r = 0; r < 4; ++r) {
                const size_t grow = m0 + wm + mi * 16 + qd * 4 + r;
#pragma unroll
                for (int ni = 0; ni < 4; ++ni)
                    Cf[grow * 1024 + c0 + wn + ni * 16 + l15] = acc[mi][ni][r];
            }
    } else {
        if (c0 < 1024) {   // K half
#pragma unroll
            for (int mi = 0; mi < MI; ++mi)
#pragma unroll
                for (int r = 0; r < 4; ++r) {
                    const size_t grow = m0 + wm + mi * 16 + qd * 4 + r;
#pragma unroll
                    for (int ni = 0; ni < 4; ++ni) {
                        const int gcol = c0 + wn + ni * 16 + l15;
                        Cf[grow * 1024 + gcol] = acc[mi][ni][r];
                        Cb[grow * 1024 + gcol] = f2bf(acc[mi][ni][r]);
                    }
                }
        } else {           // V half: row-major f32 + transposed bf16
#pragma unroll
            for (int mi = 0; mi < MI; ++mi) {
                const int growb = m0 + wm + mi * 16 + qd * 4;
                const int bb_ = growb >> 11, ss = growb & 2047;
#pragma unroll
                for (int ni = 0; ni < 4; ++ni) {
                    const int gv = c0 - 1024 + wn + ni * 16 + l15;
                    const int hh = gv >> 6, dd = gv & 63;
#pragma unroll
                    for (int r = 0; r < 4; ++r)
                        Cf2[(size_t)(growb + r) * 1024 + gv] = acc[mi][ni][r];
                    ushort4 w;
                    w.x = f2bf(acc[mi][ni][0]); w.y = f2bf(acc[mi][ni][1]);
                    w.z = f2bf(acc[mi][ni][2]); w.w = f2bf(acc[mi][ni][3]);
                    *(ushort4*)&CbT[(((size_t)bb_ * NH_ + hh) * DH_ + dd) * SQ_ + ss] = w;
                }
            }
        }
    }
}

// causal flash attention, S^T formulation; 64 q-rows/block (4 waves x 16),
// two paired q-tiles per block (qt, 31-qt) for uniform work.
__global__ __launch_bounds__(256) void attn_mfma(
    unsigned short* __restrict__ qz, const unsigned short* __restrict__ kbf,
    const unsigned short* __restrict__ vbfT)
{
    __shared__ __align__(16) unsigned short Ks[64][72];    // [kvrow][d]
    __shared__ __align__(16) unsigned short VsT[64][72];   // [d][kvrow]
    __shared__ __align__(16) unsigned short Ps[64][72];    // [qrow][kv] (wave-private rows)

    const int tid = threadIdx.x;
    const int h = blockIdx.y, b = blockIdx.z;
    const int wid = tid >> 6, lane = tid & 63;
    const int l15 = lane & 15, qd = lane >> 4;
    const int srow = tid >> 2, scol = (tid & 3) * 16;

    const size_t kbase = (size_t)b * SQ_ * DM_ + (size_t)h * DH_;
    const size_t vbase = ((size_t)b * NH_ + h) * DH_ * (size_t)SQ_;

    const f32x4 zero4 = {0.f, 0.f, 0.f, 0.f};

    for (int pass = 0; pass < 2; ++pass) {
        const int qt = pass ? blockIdx.x : (SQ_ / 64 - 1) - blockIdx.x;

        // Q fragments (B-operand: n=l15 -> qrow, k=qd*8+j -> d), direct from global
        bf16x8 qf[2];
        {
            const unsigned short* qp =
                qz + kbase + (size_t)(qt * 64 + wid * 16 + l15) * DM_ + qd * 8;
            qf[0] = *(const bf16x8*)(qp);
            qf[1] = *(const bf16x8*)(qp + 32);
        }

        f32x4 z[4];
#pragma unroll
        for (int ni = 0; ni < 4; ++ni) z[ni] = zero4;
        float m_i = -3.0e38f, l_i = 0.f;

        for (int kt = 0; kt <= qt; ++kt) {
            __syncthreads();   // prior tile's PV reads of Ks/VsT complete
            {
                const unsigned short* ks = kbf + kbase + (size_t)(kt * 64 + srow) * DM_ + scol;
                *(u16x8*)&Ks[srow][scol + 0] = *(const u16x8*)(ks + 0);
                *(u16x8*)&Ks[srow][scol + 8] = *(const u16x8*)(ks + 8);
                const unsigned short* vs = vbfT + vbase + (size_t)srow * SQ_ + kt * 64 + scol;
                *(u16x8*)&VsT[srow][scol + 0] = *(const u16x8*)(vs + 0);
                *(u16x8*)&VsT[srow][scol + 8] = *(const u16x8*)(vs + 8);
            }
            __syncthreads();

            // S^T = K Q^T : lane holds S^T[kv=mi*16+qd*4+r][q=l15]
            f32x4 s[4];
#pragma unroll
            for (int mi = 0; mi < 4; ++mi) s[mi] = zero4;
#pragma unroll
            for (int ks = 0; ks < 2; ++ks) {
#pragma unroll
                for (int mi = 0; mi < 4; ++mi) {
                    const bf16x8 af = *(const bf16x8*)&Ks[mi * 16 + l15][ks * 32 + qd * 8];
                    s[mi] = __builtin_amdgcn_mfma_f32_16x16x32_bf16(af, qf[ks], s[mi], 0, 0, 0);
                }
            }

            if (kt == qt) {   // causal mask (tile-local): kv > q
#pragma unroll
                for (int mi = 0; mi < 4; ++mi)
#pragma unroll
                    for (int r = 0; r < 4; ++r)
                        if (mi * 16 + qd * 4 + r > wid * 16 + l15) s[mi][r] = -3.0e38f;
            }

            // per-lane softmax stats for qrow=l15 (16 local + 2 shuffles)
            float mloc = -3.0e38f;
#pragma unroll
            for (int mi = 0; mi < 4; ++mi)
#pragma unroll
                for (int r = 0; r < 4; ++r) mloc = fmaxf(mloc, s[mi][r]);
            mloc = fmaxf(mloc, __shfl_xor(mloc, 16));
            mloc = fmaxf(mloc, __shfl_xor(mloc, 32));
            const float mn = fmaxf(m_i, mloc);
            const float alpha = __expf(m_i - mn);
            float rs = 0.f;
#pragma unroll
            for (int mi = 0; mi < 4; ++mi)
#pragma unroll
                for (int r = 0; r < 4; ++r) {
                    const float e = __expf(s[mi][r] - mn);
                    s[mi][r] = e;
                    rs += e;
                }
            rs += __shfl_xor(rs, 16);
            rs += __shfl_xor(rs, 32);
            l_i = l_i * alpha + rs;
            m_i = mn;

            // P store (wave-private rows), packed 4x u16
#pragma unroll
            for (int mi = 0; mi < 4; ++mi) {
                ushort4 w;
                w.x = f2bf(s[mi][0]); w.y = f2bf(s[mi][1]);
                w.z = f2bf(s[mi][2]); w.w = f2bf(s[mi][3]);
                *(ushort4*)&Ps[wid * 16 + l15][mi * 16 + qd * 4] = w;
            }

            // rescale z by alpha of qrow = qd*4+r
#pragma unroll
            for (int r = 0; r < 4; ++r) {
                const float ar = __shfl(alpha, qd * 4 + r);
#pragma unroll
                for (int ni = 0; ni < 4; ++ni) z[ni][r] *= ar;
            }

            // z += P V  (A=P from own rows; B=V^T; same-wave DS ordering)
#pragma unroll
            for (int ks = 0; ks < 2; ++ks) {
                const bf16x8 ap = *(const bf16x8*)&Ps[wid * 16 + l15][ks * 32 + qd * 8];
#pragma unroll
                for (int ni = 0; ni < 4; ++ni) {
                    const bf16x8 bv = *(const bf16x8*)&VsT[ni * 16 + l15][ks * 32 + qd * 8];
                    z[ni] = __builtin_amdgcn_mfma_f32_16x16x32_bf16(ap, bv, z[ni], 0, 0, 0);
                }
            }
        }

        const float linv = 1.0f / l_i;
#pragma unroll
        for (int r = 0; r < 4; ++r) {
            const float lr_ = __shfl(linv, qd * 4 + r);
            const size_t row = (size_t)qt * 64 + wid * 16 + qd * 4 + r;
#pragma unroll
            for (int ni = 0; ni < 4; ++ni)
                qz[kbase + row * DM_ + ni * 16 + l15] = f2bf(z[ni][r] * lr_);
        }
    }
}

extern "C" void kernel_launch(void* const* d_in, const int* in_sizes, int n_in,
                              void* d_out, int out_size, void* d_ws, size_t ws_size,
                              hipStream_t stream)
{
    const float* x_q  = (const float*)d_in[0];
    const float* x_kv = (const float*)d_in[1];
    // d_in[2] = mask (causal tril) -- computed analytically
    const float* W_Q  = (const float*)d_in[3];
    const float* W_K  = (const float*)d_in[4];
    const float* W_V  = (const float*)d_in[5];
    const float* W_O  = (const float*)d_in[6];
    const float* b_Q  = (const float*)d_in[7];
    const float* b_K  = (const float*)d_in[8];
    const float* b_V  = (const float*)d_in[9];
    const float* b_O  = (const float*)d_in[10];
    const float* ln1w = (const float*)d_in[11];
    const float* ln1b = (const float*)d_in[12];
    const float* ln2w = (const float*)d_in[13];
    const float* ln2b = (const float*)d_in[14];

    const size_t NTOK = (size_t)B_ * SQ_;          // 4096
    float* out  = (float*)d_out;
    float* kout = out + NTOK * DM_;
    float* vout = kout + NTOK * DM_;

    unsigned short* wsu  = (unsigned short*)d_ws;
    unsigned short* WTq  = wsu;                        // 1M elems
    unsigned short* WTkv = WTq + (1u << 20);           // 2M elems (K^T rows 0..1023, V^T rows 1024..2047)
    unsigned short* WTo  = WTkv + (2u << 20);          // 1M
    unsigned short* qz   = WTo + (1u << 20);           // 4M
    unsigned short* kbf  = qz + (1u << 22);            // 4M
    unsigned short* vbfT = kbf + (1u << 22);           // 4M  -> 32 MiB total

    transpose_w<<<dim3(16, 1, 16), 256, 0, stream>>>(W_Q, WTq, 1024, 64);
    transpose_w<<<dim3(16, 1, 16), 256, 0, stream>>>(W_K, WTkv, 1024, 64);
    transpose_w<<<dim3(16, 1, 16), 256, 0, stream>>>(W_V, WTkv + (1u << 20), 1024, 64);
    transpose_w<<<dim3(16, 16, 1), 256, 0, stream>>>(W_O, WTo, 1024, 1024);

    // Q: 128x64 tiles, grid 512
    mfma_gemm<64, 0, 0><<<dim3(16, 32), 256, 0, stream>>>(
        x_q, WTq, b_Q, nullptr, ln1w, ln1b, nullptr, nullptr, qz, nullptr);
    // K+V fused: N=2048, 128x128 tiles, grid 512
    mfma_gemm<128, 0, 1><<<dim3(16, 32), 256, 0, stream>>>(
        x_kv, WTkv, b_K, b_V, ln2w, ln2b, kout, vout, kbf, vbfT);

    attn_mfma<<<dim3(16, NH_, B_), 256, 0, stream>>>(qz, kbf, vbfT);

    // O: 128x64 tiles, grid 512
    mfma_gemm<64, 1, 2><<<dim3(16, 32), 256, 0, stream>>>(
        qz, WTo, b_O, nullptr, nullptr, nullptr, out, nullptr, nullptr, nullptr);
}